// Round 1
// baseline (183.189 us; speedup 1.0000x reference)
//
#include <hip/hip_runtime.h>

// ---------------------------------------------------------------------------
// LeNet5-KAN on MI355X.
// Pipeline: prep (repack weights) -> conv1+pool -> conv2+pool -> fc1/2/3.
// Spline: uniform knots => cardinal cubic B-spline closed form.
//   u = (x + 2.2)/0.4 = 2.5x + 5.5 ; cell i = floor(u), w = u - i
//   nonzero bases j=i-3..i: {(1-w)^3, 3w^3-6w^2+4, -3w^3+3w^2+3w+1, w^3}/6
//   valid iff 0 <= u < 11, basis index clipped to [0,8).
// Feature vector per input element: f[0..7] = bases, f[8] = relu(x).
// Weights repacked so f dot w row gives base+spline contribution.
// ---------------------------------------------------------------------------

#define ONE_SIXTH 0.16666666666666666f

__device__ __forceinline__ void spline_feats(float v, float* __restrict__ f) {
    float u  = 2.5f * v + 5.5f;
    bool valid = (u >= 0.0f) && (u < 11.0f);
    float fi = floorf(u);
    int   i  = (int)fi;
    float w  = u - fi;
    float omw = 1.0f - w;
    float w2 = w * w, w3 = w2 * w;
    float c0 = omw * omw * omw * ONE_SIXTH;
    float c1 = (3.0f * w3 - 6.0f * w2 + 4.0f) * ONE_SIXTH;
    float c2 = (-3.0f * w3 + 3.0f * w2 + 3.0f * w + 1.0f) * ONE_SIXTH;
    float c3 = w3 * ONE_SIXTH;
    int j0 = i - 3;
#pragma unroll
    for (int j = 0; j < 8; ++j) {
        int d = j - j0;
        float val = (d == 0) ? c0 : (d == 1) ? c1 : (d == 2) ? c2 : (d == 3) ? c3 : 0.0f;
        f[j] = valid ? val : 0.0f;
    }
    f[8] = fmaxf(v, 0.0f);
}

// ---------------------------------------------------------------------------
// K0: repack weights.
// W1p[tap][64]: slots o*9+k (o<6,k<9): k<8 -> spline_w*scaler, k==8 -> base_w.
// W2p[row=tap*4+g][40]: slots oo*9+k with o = g*4+oo (o<16), same scheme.
// ---------------------------------------------------------------------------
__global__ __launch_bounds__(256) void k_prep(
    const float* __restrict__ c1_bw, const float* __restrict__ c1_sw,
    const float* __restrict__ c1_sc,
    const float* __restrict__ c2_bw, const float* __restrict__ c2_sw,
    const float* __restrict__ c2_sc,
    float* __restrict__ W1p, float* __restrict__ W2p)
{
    int t = blockIdx.x * 256 + threadIdx.x;
    if (t < 1600) {                       // 25 taps * 64
        int tap = t >> 6, s = t & 63;
        float v = 0.0f;
        if (s < 54) {
            int o = s / 9, k = s % 9;
            v = (k == 8) ? c1_bw[o * 25 + tap]
                         : c1_sw[(o * 25 + tap) * 8 + k] * c1_sc[o * 25 + tap];
        }
        W1p[t] = v;
    }
    if (t < 24000) {                      // 600 rows * 40
        int row = t / 40, s = t % 40;
        int tap = row >> 2, g = row & 3;
        float v = 0.0f;
        if (s < 36) {
            int oo = s / 9, k = s % 9;
            int o = g * 4 + oo;
            v = (k == 8) ? c2_bw[o * 150 + tap]
                         : c2_sw[(o * 150 + tap) * 8 + k] * c2_sc[o * 150 + tap];
        }
        W2p[t] = v;
    }
}

// ---------------------------------------------------------------------------
// K1: conv1 (25 taps, 6 out ch) + 2x2 avg pool. One block per image.
// 576 threads: one per conv output pixel (24x24), all 6 channels.
// ---------------------------------------------------------------------------
__global__ __launch_bounds__(576) void k_conv1(
    const float* __restrict__ x, const float* __restrict__ W1p,
    float* __restrict__ h1)
{
    __shared__ float feat[784][12];    // 9 used, pad to 12 for 16B-aligned rows
    __shared__ float cstage[6][576];   // conv output staging for pooling
    const int b = blockIdx.x;
    const int tid = threadIdx.x;
    const float* xb = x + b * 784;

    for (int e = tid; e < 784; e += 576)
        spline_feats(xb[e], &feat[e][0]);
    __syncthreads();

    {
        const int y = tid / 24, xc = tid % 24;
        float acc[6] = {0, 0, 0, 0, 0, 0};
#pragma unroll
        for (int dy = 0; dy < 5; ++dy) {
#pragma unroll
            for (int dx = 0; dx < 5; ++dx) {
                const int tap = dy * 5 + dx;
                const float* f = &feat[(y + dy) * 28 + (xc + dx)][0];
                const float4 s0 = *(const float4*)(f);
                const float4 s1 = *(const float4*)(f + 4);
                const float  rr = f[8];
                const float* wt = W1p + tap * 64;   // wave-uniform -> s_load
#pragma unroll
                for (int o = 0; o < 6; ++o) {
                    const float* wo = wt + o * 9;
                    acc[o] += s0.x * wo[0] + s0.y * wo[1] + s0.z * wo[2] + s0.w * wo[3]
                            + s1.x * wo[4] + s1.y * wo[5] + s1.z * wo[6] + s1.w * wo[7]
                            + rr * wo[8];
                }
            }
        }
#pragma unroll
        for (int o = 0; o < 6; ++o) cstage[o][tid] = acc[o];
    }
    __syncthreads();

    for (int idx = tid; idx < 864; idx += 576) {   // 6 ch * 144 pooled px
        int o = idx / 144, p = idx % 144;
        int py = p / 12, px = p % 12;
        int cb = (2 * py) * 24 + 2 * px;
        float s = cstage[o][cb] + cstage[o][cb + 1] +
                  cstage[o][cb + 24] + cstage[o][cb + 25];
        h1[(b * 6 + o) * 144 + p] = 0.25f * s;
    }
}

// ---------------------------------------------------------------------------
// K2: conv2 (150 taps = 6ch x 25 spatial, 16 out ch) + pool. One block/image.
// 256 threads = 64 px  x  4 channel-groups (4 ch each, wave-uniform group).
// ---------------------------------------------------------------------------
__global__ __launch_bounds__(256) void k_conv2(
    const float* __restrict__ h1, const float* __restrict__ W2p,
    float* __restrict__ h2)
{
    __shared__ float feat[864][12];    // 6*144 elements
    __shared__ float cstage[64][16];
    const int b = blockIdx.x;
    const int tid = threadIdx.x;
    const float* hb = h1 + b * 864;

    for (int e = tid; e < 864; e += 256)
        spline_feats(hb[e], &feat[e][0]);
    __syncthreads();

    {
        const int g  = __builtin_amdgcn_readfirstlane(tid >> 6); // 0..3, uniform
        const int px = tid & 63;
        const int y = px >> 3, xc = px & 7;
        float acc[4] = {0, 0, 0, 0};
        for (int c = 0; c < 6; ++c) {
#pragma unroll
            for (int dy = 0; dy < 5; ++dy) {
#pragma unroll
                for (int dx = 0; dx < 5; ++dx) {
                    const int tap = c * 25 + dy * 5 + dx;
                    const float* f = &feat[c * 144 + (y + dy) * 12 + (xc + dx)][0];
                    const float4 s0 = *(const float4*)(f);
                    const float4 s1 = *(const float4*)(f + 4);
                    const float  rr = f[8];
                    const float* wt = W2p + (tap * 4 + g) * 40;  // uniform -> s_load
#pragma unroll
                    for (int oo = 0; oo < 4; ++oo) {
                        const float* wo = wt + oo * 9;
                        acc[oo] += s0.x * wo[0] + s0.y * wo[1] + s0.z * wo[2] + s0.w * wo[3]
                                 + s1.x * wo[4] + s1.y * wo[5] + s1.z * wo[6] + s1.w * wo[7]
                                 + rr * wo[8];
                    }
                }
            }
        }
#pragma unroll
        for (int oo = 0; oo < 4; ++oo) cstage[px][g * 4 + oo] = acc[oo];
    }
    __syncthreads();

    {   // 256 outputs: tid = o*16 + p ; h2 row layout [16][4][4] flattened
        const int o = tid >> 4, p = tid & 15;
        const int py = p >> 2, px = p & 3;
        const int cb = (2 * py) * 8 + 2 * px;
        float s = cstage[cb][o] + cstage[cb + 1][o] +
                  cstage[cb + 8][o] + cstage[cb + 9][o];
        h2[b * 256 + tid] = 0.25f * s;
    }
}

// ---------------------------------------------------------------------------
// K3: fc1(relu) -> fc2(relu) -> fc3. One block = 8 batch rows, 256 threads.
// ---------------------------------------------------------------------------
__global__ __launch_bounds__(256) void k_fc(
    const float* __restrict__ h2,
    const float* __restrict__ w1, const float* __restrict__ b1,
    const float* __restrict__ w2, const float* __restrict__ b2,
    const float* __restrict__ w3, const float* __restrict__ b3,
    float* __restrict__ out)
{
    __shared__ float xin[8][260];   // pad 256->260 to break bank aliasing
    __shared__ float a1[8][120];
    __shared__ float a2[8][84];
    const int tid = threadIdx.x;
    const int r0 = blockIdx.x * 8;

    for (int i = tid; i < 2048; i += 256)
        xin[i >> 8][i & 255] = h2[r0 * 256 + i];
    __syncthreads();

    for (int idx = tid; idx < 960; idx += 256) {      // 120 out x 8 rows
        const int o = idx >> 3, r = idx & 7;
        const float* w = w1 + o * 256;
        float s = 0.0f;
#pragma unroll 8
        for (int k = 0; k < 64; ++k) {
            float4 wv = ((const float4*)w)[k];
            float4 xv = *(const float4*)(&xin[r][k * 4]);
            s += wv.x * xv.x + wv.y * xv.y + wv.z * xv.z + wv.w * xv.w;
        }
        a1[r][o] = fmaxf(s + b1[o], 0.0f);
    }
    __syncthreads();

    for (int idx = tid; idx < 672; idx += 256) {      // 84 out x 8 rows
        const int o = idx >> 3, r = idx & 7;
        const float* w = w2 + o * 120;
        float s = 0.0f;
#pragma unroll
        for (int k = 0; k < 30; ++k) {
            float4 wv = ((const float4*)w)[k];
            float4 xv = *(const float4*)(&a1[r][k * 4]);
            s += wv.x * xv.x + wv.y * xv.y + wv.z * xv.z + wv.w * xv.w;
        }
        a2[r][o] = fmaxf(s + b2[o], 0.0f);
    }
    __syncthreads();

    for (int idx = tid; idx < 496; idx += 256) {      // 62 out x 8 rows
        const int o = idx >> 3, r = idx & 7;
        const float* w = w3 + o * 84;
        float s = 0.0f;
#pragma unroll
        for (int k = 0; k < 21; ++k) {
            float4 wv = ((const float4*)w)[k];
            float4 xv = *(const float4*)(&a2[r][k * 4]);
            s += wv.x * xv.x + wv.y * xv.y + wv.z * xv.z + wv.w * xv.w;
        }
        out[(r0 + r) * 62 + o] = s + b3[o];
    }
}

// ---------------------------------------------------------------------------
extern "C" void kernel_launch(void* const* d_in, const int* in_sizes, int n_in,
                              void* d_out, int out_size, void* d_ws, size_t ws_size,
                              hipStream_t stream)
{
    (void)in_sizes; (void)n_in; (void)out_size; (void)ws_size;
    const float* x      = (const float*)d_in[0];
    const float* c1_bw  = (const float*)d_in[1];
    const float* c1_sw  = (const float*)d_in[2];
    const float* c1_sc  = (const float*)d_in[3];
    const float* c2_bw  = (const float*)d_in[4];
    const float* c2_sw  = (const float*)d_in[5];
    const float* c2_sc  = (const float*)d_in[6];
    const float* fc1_w  = (const float*)d_in[7];
    const float* fc1_b  = (const float*)d_in[8];
    const float* fc2_w  = (const float*)d_in[9];
    const float* fc2_b  = (const float*)d_in[10];
    const float* fc3_w  = (const float*)d_in[11];
    const float* fc3_b  = (const float*)d_in[12];
    float* out = (float*)d_out;

    float* ws  = (float*)d_ws;
    float* W1p = ws;                 // 1600
    float* W2p = ws + 1600;          // 24000
    float* h1  = ws + 25600;         // 1024*6*144 = 884736
    float* h2  = ws + 910336;        // 1024*256   = 262144

    hipLaunchKernelGGL(k_prep, dim3(94), dim3(256), 0, stream,
                       c1_bw, c1_sw, c1_sc, c2_bw, c2_sw, c2_sc, W1p, W2p);
    hipLaunchKernelGGL(k_conv1, dim3(1024), dim3(576), 0, stream, x, W1p, h1);
    hipLaunchKernelGGL(k_conv2, dim3(1024), dim3(256), 0, stream, h1, W2p, h2);
    hipLaunchKernelGGL(k_fc, dim3(128), dim3(256), 0, stream,
                       h2, fc1_w, fc1_b, fc2_w, fc2_b, fc3_w, fc3_b, out);
}